// Round 3
// baseline (316.310 us; speedup 1.0000x reference)
//
#include <hip/hip_runtime.h>

typedef unsigned short u16;
typedef unsigned int u32;
typedef __attribute__((ext_vector_type(8))) __bf16 bf16x8;
typedef __attribute__((ext_vector_type(4))) float f32x4;

#define EMBED 1024
#define NB 2
#define LQ 2048
#define HEADS 16
#define DH 64
// log2(e) / sqrt(64) -- folded into Q at projection time
#define QSCALE 0.18033688011112042f

__device__ __forceinline__ u16 f2bf(float f) {
  u32 u = __float_as_uint(f);
  u32 r = (u + 0x7FFFu + ((u >> 16) & 1u)) >> 16;  // RNE
  return (u16)r;
}

__device__ __forceinline__ void glds16(const void* g, void* l) {
  __builtin_amdgcn_global_load_lds((const __attribute__((address_space(1))) void*)g,
                                   (__attribute__((address_space(3))) void*)l, 16, 0, 0);
}

__device__ __forceinline__ f32x4 mfma16(bf16x8 a, bf16x8 b, f32x4 c) {
  return __builtin_amdgcn_mfma_f32_16x16x32_bf16(a, b, c, 0, 0, 0);
}

// ---------------- cast fp32 -> bf16 for activations + weights ----------------
__global__ __launch_bounds__(256) void cast_kernel(
    const float* __restrict__ q, const float* __restrict__ kv,
    const float* __restrict__ wq, const float* __restrict__ wk,
    const float* __restrict__ wv, const float* __restrict__ wo,
    u16* __restrict__ qb, u16* __restrict__ kvb, u16* __restrict__ wqb,
    u16* __restrict__ wkb, u16* __restrict__ wvb, u16* __restrict__ wob) {
  int bid = blockIdx.x;
  const float* src;
  u16* dst;
  long base;
  if (bid < 2048) {
    src = q; dst = qb; base = (long)bid * 2048;
  } else if (bid < 4096) {
    src = kv; dst = kvb; base = (long)(bid - 2048) * 2048;
  } else {
    int wsel = (bid - 4096) >> 9;
    int wb = (bid - 4096) & 511;
    if (wsel == 0) { src = wq; dst = wqb; }
    else if (wsel == 1) { src = wk; dst = wkb; }
    else if (wsel == 2) { src = wv; dst = wvb; }
    else { src = wo; dst = wob; }
    base = (long)wb * 2048;
  }
  long e = base + (long)threadIdx.x * 8;
  float4 f0 = *(const float4*)(src + e);
  float4 f1 = *(const float4*)(src + e + 4);
  uint4 o;
  o.x = (u32)f2bf(f0.x) | ((u32)f2bf(f0.y) << 16);
  o.y = (u32)f2bf(f0.z) | ((u32)f2bf(f0.w) << 16);
  o.z = (u32)f2bf(f1.x) | ((u32)f2bf(f1.y) << 16);
  o.w = (u32)f2bf(f1.z) | ((u32)f2bf(f1.w) << 16);
  *(uint4*)(dst + e) = o;
}

// ---------------- GEMM: C = A @ W^T (+bias, mode-specific epilogue) ----------
// mode 0: Q -> [bh][L][64], scaled by QSCALE; 1: K -> same layout unscaled;
// mode 2: V -> [bh][64][L] (transposed); mode 3: fp32 out = acc + bias + resid.
template <int IT>
__device__ __forceinline__ void gemm_core(
    u16* As, u16* Bs, const u16* __restrict__ A, const u16* __restrict__ W,
    const float* __restrict__ bias, const float* __restrict__ resid,
    void* __restrict__ outp, int mode, int bx, int by) {
  const int K = EMBED;
  const int TM = IT * 32;
  const int tid = threadIdx.x;
  const int lane = tid & 63;
  const int wv = tid >> 6;
  const int wm = wv >> 1, wn = wv & 1;
  const int l16 = lane & 15, quad = lane >> 4;
  const long tile_m = (long)bx * TM;
  const long tile_n = (long)by * 128;

  f32x4 z4 = {0.f, 0.f, 0.f, 0.f};
  f32x4 acc[IT][4];
#pragma unroll
  for (int i = 0; i < IT; i++)
#pragma unroll
    for (int j = 0; j < 4; j++) acc[i][j] = z4;

  for (int k0 = 0; k0 < K; k0 += 32) {
#pragma unroll
    for (int it = 0; it < TM / 64; it++) {
      int lin = it * 256 + tid;
      int row = lin >> 2, cc = lin & 3;
      glds16(A + (tile_m + row) * K + k0 + ((cc ^ ((row >> 1) & 3)) << 3), As + lin * 8);
    }
#pragma unroll
    for (int it = 0; it < 2; it++) {
      int lin = it * 256 + tid;
      int row = lin >> 2, cc = lin & 3;
      glds16(W + (tile_n + row) * K + k0 + ((cc ^ ((row >> 1) & 3)) << 3), Bs + lin * 8);
    }
    __syncthreads();
    bf16x8 af[IT], bfr[4];
#pragma unroll
    for (int i = 0; i < IT; i++) {
      int row = wm * (IT * 16) + i * 16 + l16;
      af[i] = *(const bf16x8*)(As + row * 32 + ((quad ^ ((row >> 1) & 3)) << 3));
    }
#pragma unroll
    for (int j = 0; j < 4; j++) {
      int row = wn * 64 + j * 16 + l16;
      bfr[j] = *(const bf16x8*)(Bs + row * 32 + ((quad ^ ((row >> 1) & 3)) << 3));
    }
#pragma unroll
    for (int i = 0; i < IT; i++)
#pragma unroll
      for (int j = 0; j < 4; j++) acc[i][j] = mfma16(af[i], bfr[j], acc[i][j]);
    __syncthreads();
  }

  // epilogue: C/D layout col=lane&15, row=quad*4+r
#pragma unroll
  for (int j = 0; j < 4; j++) {
    int gn = (int)tile_n + wn * 64 + j * 16 + l16;
    float bv = bias[gn];
#pragma unroll
    for (int i = 0; i < IT; i++) {
#pragma unroll
      for (int r = 0; r < 4; r++) {
        long gm = tile_m + wm * (IT * 16) + i * 16 + quad * 4 + r;
        float v = acc[i][j][r] + bv;
        if (mode == 3) {
          long idx = gm * EMBED + gn;
          ((float*)outp)[idx] = v + resid[idx];
        } else {
          if (mode == 0) v *= QSCALE;
          int b = (int)(gm >> 11), l = (int)(gm & 2047);
          int h = gn >> 6, dh = gn & 63;
          long idx;
          if (mode == 2)
            idx = (long)((b * HEADS + h) * DH + dh) * LQ + l;       // V transposed
          else
            idx = (long)((b * HEADS + h) * LQ + l) * DH + dh;       // Q, K
          ((u16*)outp)[idx] = f2bf(v);
        }
      }
    }
  }
}

__global__ __launch_bounds__(256) void qkv_kernel(
    const u16* __restrict__ qb, const u16* __restrict__ kvb,
    const u16* __restrict__ wqb, const u16* __restrict__ wkb, const u16* __restrict__ wvb,
    const float* __restrict__ bq, const float* __restrict__ bk, const float* __restrict__ bv,
    u16* __restrict__ Qh, u16* __restrict__ Kh, u16* __restrict__ Vt) {
  __shared__ u16 As[128 * 32];
  __shared__ u16 Bs[128 * 32];
  if (blockIdx.z == 0)      gemm_core<4>(As, Bs, qb,  wqb, bq, nullptr, Qh, 0, blockIdx.x, blockIdx.y);
  else if (blockIdx.z == 1) gemm_core<4>(As, Bs, kvb, wkb, bk, nullptr, Kh, 1, blockIdx.x, blockIdx.y);
  else                      gemm_core<4>(As, Bs, kvb, wvb, bv, nullptr, Vt, 2, blockIdx.x, blockIdx.y);
}

__global__ __launch_bounds__(256) void oproj_kernel(
    const u16* __restrict__ ctx, const u16* __restrict__ wob,
    const float* __restrict__ bo, const float* __restrict__ resid, float* __restrict__ out) {
  __shared__ u16 As[64 * 32];
  __shared__ u16 Bs[128 * 32];
  gemm_core<2>(As, Bs, ctx, wob, bo, resid, out, 3, blockIdx.x, blockIdx.y);
}

// ---------------- flash attention, transposed formulation ----------------
// S^T = K.Q^T (Q B-frags hoisted); per-lane scalar lsum; P^T packed b64
// writes, same-wave rows => no barrier; O^T = V^T.P^T with V A-frags loaded
// DIRECTLY from global (contiguous 16B chunks; L1/L2 path parallel to LDS).
__global__ __launch_bounds__(256) void attn_kernel(
    const u16* __restrict__ Qh, const u16* __restrict__ Kh,
    const u16* __restrict__ Vt, u16* __restrict__ ctx) {
  __shared__ u16 Qs[64 * 64];    // 8 KB
  __shared__ u16 Ks[64 * 64];    // 8 KB
  __shared__ u16 Pts[64 * 64];   // 8 KB  P^T [qrow][key]
  const int tid = threadIdx.x;
  const int lane = tid & 63;
  const int wv = tid >> 6;            // wave owns q rows wv*16 .. wv*16+15
  const int l16 = lane & 15, quad = lane >> 4;
  const int qt = blockIdx.x, bh = blockIdx.y;
  const long qoff = (long)bh * (LQ * DH) + (long)qt * (64 * DH);
  const long koff = (long)bh * (LQ * DH);
  const long voff = (long)bh * (DH * LQ);
  const int qbase = wv * 16;

  // stage Q tile 64x64 (row-swizzled 16B chunks)
#pragma unroll
  for (int it = 0; it < 2; it++) {
    int lin = it * 256 + tid;
    int row = lin >> 3, cc = lin & 7;
    glds16(Qh + qoff + row * 64 + ((cc ^ (row & 7)) << 3), Qs + lin * 8);
  }
  __syncthreads();

  // hoisted Q B-fragments: n = qbase+l16, k = ks*32+quad*8+j
  bf16x8 bq[2];
  {
    int row = qbase + l16;
#pragma unroll
    for (int ks = 0; ks < 2; ks++)
      bq[ks] = *(const bf16x8*)(Qs + row * 64 + (((ks * 4 + quad) ^ (row & 7)) << 3));
  }

  f32x4 z4 = {0.f, 0.f, 0.f, 0.f};
  f32x4 ot[4];
#pragma unroll
  for (int dm = 0; dm < 4; dm++) ot[dm] = z4;
  float lsum = 0.f;

  for (int kt = 0; kt < 32; kt++) {
    // stage K (prev trailing barrier guarantees Ks free)
#pragma unroll
    for (int it = 0; it < 2; it++) {
      int lin = it * 256 + tid;
      int row = lin >> 3, cc = lin & 7;
      glds16(Kh + koff + (long)(kt * 64 + row) * 64 + ((cc ^ (row & 7)) << 3), Ks + lin * 8);
    }
    __syncthreads();

    // V^T A-fragments direct from global: m = dm*16+l16 (d), k = key
    bf16x8 av[4][2];
#pragma unroll
    for (int dm = 0; dm < 4; dm++)
#pragma unroll
      for (int ks = 0; ks < 2; ks++)
        av[dm][ks] = *(const bf16x8*)(Vt + voff + (long)(dm * 16 + l16) * LQ +
                                      kt * 64 + ks * 32 + quad * 8);

    // S^T = K . Q^T : 64 keys x wave's 16 qrows
    f32x4 st[4];
#pragma unroll
    for (int mt = 0; mt < 4; mt++) st[mt] = z4;
#pragma unroll
    for (int ks = 0; ks < 2; ks++) {
#pragma unroll
      for (int mt = 0; mt < 4; mt++) {
        int row = mt * 16 + l16;
        bf16x8 ak = *(const bf16x8*)(Ks + row * 64 + (((ks * 4 + quad) ^ (row & 7)) << 3));
        st[mt] = mfma16(ak, bq[ks], st[mt]);
      }
    }

    // p = 2^s; lane's 16 scores all belong to qrow qbase+l16, keys
    // mt*16+quad*4+r (4 consecutive) -> pack 4 bf16 -> one ds_write_b64
    {
      int prow = qbase + l16;
#pragma unroll
      for (int mt = 0; mt < 4; mt++) {
        float p0 = exp2f(st[mt][0]), p1 = exp2f(st[mt][1]);
        float p2 = exp2f(st[mt][2]), p3 = exp2f(st[mt][3]);
        lsum += (p0 + p1) + (p2 + p3);
        u32 lo = __builtin_amdgcn_perm(__float_as_uint(p1), __float_as_uint(p0), 0x07060302u);
        u32 hi = __builtin_amdgcn_perm(__float_as_uint(p3), __float_as_uint(p2), 0x07060302u);
        int c = mt * 2 + (quad >> 1);
        uint2 pk;
        pk.x = lo; pk.y = hi;
        *(uint2*)(Pts + prow * 64 + ((c ^ (prow & 7)) << 3) + (quad & 1) * 4) = pk;
      }
    }

    // O^T += V^T . P^T  (P rows are same-wave => no barrier needed)
#pragma unroll
    for (int ks = 0; ks < 2; ks++) {
      int prow = qbase + l16;
      bf16x8 bp = *(const bf16x8*)(Pts + prow * 64 + (((ks * 4 + quad) ^ (prow & 7)) << 3));
#pragma unroll
      for (int dm = 0; dm < 4; dm++)
        ot[dm] = mfma16(av[dm][ks], bp, ot[dm]);
    }
    __syncthreads();
  }

  // lsum: reduce across the 4 quads holding each qrow
  lsum += __shfl_xor(lsum, 16);
  lsum += __shfl_xor(lsum, 32);
  float inv = 1.0f / lsum;

  // epilogue: O^T C-layout col=l16=qrow, row=quad*4+r -> d=dm*16+quad*4+r
  const int b = bh >> 4, h = bh & 15;
  int qrow = qt * 64 + qbase + l16;
  long base = (long)(b * LQ + qrow) * EMBED + h * DH;
#pragma unroll
  for (int dm = 0; dm < 4; dm++) {
    u32 lo = (u32)f2bf(ot[dm][0] * inv) | ((u32)f2bf(ot[dm][1] * inv) << 16);
    u32 hi = (u32)f2bf(ot[dm][2] * inv) | ((u32)f2bf(ot[dm][3] * inv) << 16);
    uint2 pk;
    pk.x = lo; pk.y = hi;
    *(uint2*)(ctx + base + dm * 16 + quad * 4) = pk;
  }
}

// ---------------- LayerNorm in place on d_out ----------------
__global__ __launch_bounds__(256) void ln_kernel(
    float* __restrict__ x, const float* __restrict__ gamma, const float* __restrict__ beta) {
  __shared__ float red[8];
  const int tid = threadIdx.x;
  const long row = blockIdx.x;
  float4 v = *(const float4*)(x + row * EMBED + tid * 4);
  float s = v.x + v.y + v.z + v.w;
  float sq = v.x * v.x + v.y * v.y + v.z * v.z + v.w * v.w;
#pragma unroll
  for (int off = 1; off < 64; off <<= 1) {
    s += __shfl_xor(s, off);
    sq += __shfl_xor(sq, off);
  }
  if ((tid & 63) == 0) {
    red[(tid >> 6) * 2] = s;
    red[(tid >> 6) * 2 + 1] = sq;
  }
  __syncthreads();
  s = red[0] + red[2] + red[4] + red[6];
  sq = red[1] + red[3] + red[5] + red[7];
  float mu = s * (1.f / EMBED);
  float var = sq * (1.f / EMBED) - mu * mu;
  float rstd = rsqrtf(var + 1e-5f);
  float4 g = *(const float4*)(gamma + tid * 4);
  float4 bt = *(const float4*)(beta + tid * 4);
  float4 ov;
  ov.x = (v.x - mu) * rstd * g.x + bt.x;
  ov.y = (v.y - mu) * rstd * g.y + bt.y;
  ov.z = (v.z - mu) * rstd * g.z + bt.z;
  ov.w = (v.w - mu) * rstd * g.w + bt.w;
  *(float4*)(x + row * EMBED + tid * 4) = ov;
}

extern "C" void kernel_launch(void* const* d_in, const int* in_sizes, int n_in,
                              void* d_out, int out_size, void* d_ws, size_t ws_size,
                              hipStream_t stream) {
  const float* q     = (const float*)d_in[0];
  const float* kv    = (const float*)d_in[1];
  // d_in[2] = prompt_size (0, unused)
  const float* Wq    = (const float*)d_in[3];
  const float* bq    = (const float*)d_in[4];
  const float* Wk    = (const float*)d_in[5];
  const float* bk    = (const float*)d_in[6];
  const float* Wv    = (const float*)d_in[7];
  const float* bv    = (const float*)d_in[8];
  const float* Wo    = (const float*)d_in[9];
  const float* bo    = (const float*)d_in[10];
  const float* gamma = (const float*)d_in[11];
  const float* beta  = (const float*)d_in[12];

  char* ws = (char*)d_ws;
  u16* qb  = (u16*)(ws + (0l  << 20));  // 8 MB
  u16* kvb = (u16*)(ws + (8l  << 20));  // 8 MB
  u16* wqb = (u16*)(ws + (16l << 20));  // 2 MB
  u16* wkb = (u16*)(ws + (18l << 20));
  u16* wvb = (u16*)(ws + (20l << 20));
  u16* wob = (u16*)(ws + (22l << 20));
  u16* Qh  = (u16*)(ws + (24l << 20));  // 8 MB [bh][L][64] (pre-scaled by QSCALE)
  u16* Kh  = (u16*)(ws + (32l << 20));  // 8 MB [bh][L][64]
  u16* Vt  = (u16*)(ws + (40l << 20));  // 8 MB [bh][64][L]
  u16* ctx = (u16*)(ws + (48l << 20));  // 8 MB [B][L][E]   (total 56 MB)
  float* out = (float*)d_out;

  cast_kernel<<<6144, 256, 0, stream>>>(q, kv, Wq, Wk, Wv, Wo, qb, kvb, wqb, wkb, wvb, wob);
  qkv_kernel<<<dim3(32, 8, 3), 256, 0, stream>>>(qb, kvb, wqb, wkb, wvb, bq, bk, bv, Qh, Kh, Vt);
  attn_kernel<<<dim3(32, 32), 256, 0, stream>>>(Qh, Kh, Vt, ctx);
  oproj_kernel<<<dim3(64, 8), 256, 0, stream>>>(ctx, wob, bo, q, out);
  ln_kernel<<<4096, 256, 0, stream>>>(out, gamma, beta);
}

// Round 4
// 248.058 us; speedup vs baseline: 1.2751x; 1.2751x over previous
//
#include <hip/hip_runtime.h>

typedef unsigned short u16;
typedef unsigned int u32;
typedef __attribute__((ext_vector_type(8))) __bf16 bf16x8;
typedef __attribute__((ext_vector_type(4))) float f32x4;
typedef __attribute__((ext_vector_type(16))) float f32x16;

#define EMBED 1024
#define NB 2
#define LQ 2048
#define HEADS 16
#define DH 64
// log2(e) / sqrt(64) -- folded into Q at projection time
#define QSCALE 0.18033688011112042f

__device__ __forceinline__ u16 f2bf(float f) {
  u32 u = __float_as_uint(f);
  u32 r = (u + 0x7FFFu + ((u >> 16) & 1u)) >> 16;  // RNE
  return (u16)r;
}

__device__ __forceinline__ void glds16(const void* g, void* l) {
  __builtin_amdgcn_global_load_lds((const __attribute__((address_space(1))) void*)g,
                                   (__attribute__((address_space(3))) void*)l, 16, 0, 0);
}

__device__ __forceinline__ f32x4 mfma16(bf16x8 a, bf16x8 b, f32x4 c) {
  return __builtin_amdgcn_mfma_f32_16x16x32_bf16(a, b, c, 0, 0, 0);
}
__device__ __forceinline__ f32x16 mfma32(bf16x8 a, bf16x8 b, f32x16 c) {
  return __builtin_amdgcn_mfma_f32_32x32x16_bf16(a, b, c, 0, 0, 0);
}

// ---------------- cast fp32 -> bf16 for activations + weights ----------------
__global__ __launch_bounds__(256) void cast_kernel(
    const float* __restrict__ q, const float* __restrict__ kv,
    const float* __restrict__ wq, const float* __restrict__ wk,
    const float* __restrict__ wv, const float* __restrict__ wo,
    u16* __restrict__ qb, u16* __restrict__ kvb, u16* __restrict__ wqb,
    u16* __restrict__ wkb, u16* __restrict__ wvb, u16* __restrict__ wob) {
  int bid = blockIdx.x;
  const float* src;
  u16* dst;
  long base;
  if (bid < 2048) {
    src = q; dst = qb; base = (long)bid * 2048;
  } else if (bid < 4096) {
    src = kv; dst = kvb; base = (long)(bid - 2048) * 2048;
  } else {
    int wsel = (bid - 4096) >> 9;
    int wb = (bid - 4096) & 511;
    if (wsel == 0) { src = wq; dst = wqb; }
    else if (wsel == 1) { src = wk; dst = wkb; }
    else if (wsel == 2) { src = wv; dst = wvb; }
    else { src = wo; dst = wob; }
    base = (long)wb * 2048;
  }
  long e = base + (long)threadIdx.x * 8;
  float4 f0 = *(const float4*)(src + e);
  float4 f1 = *(const float4*)(src + e + 4);
  uint4 o;
  o.x = (u32)f2bf(f0.x) | ((u32)f2bf(f0.y) << 16);
  o.y = (u32)f2bf(f0.z) | ((u32)f2bf(f0.w) << 16);
  o.z = (u32)f2bf(f1.x) | ((u32)f2bf(f1.y) << 16);
  o.w = (u32)f2bf(f1.z) | ((u32)f2bf(f1.w) << 16);
  *(uint4*)(dst + e) = o;
}

// ---------------- GEMM: C = A @ W^T (+bias, mode-specific epilogue) ----------
// mode 0: Q -> [bh][L][64], scaled by QSCALE; 1: K -> same layout unscaled;
// mode 2: V -> [bh][64][L] (transposed); mode 3: fp32 out = acc + bias + resid.
template <int IT>
__device__ __forceinline__ void gemm_core(
    u16* As, u16* Bs, const u16* __restrict__ A, const u16* __restrict__ W,
    const float* __restrict__ bias, const float* __restrict__ resid,
    void* __restrict__ outp, int mode, int bx, int by) {
  const int K = EMBED;
  const int TM = IT * 32;
  const int tid = threadIdx.x;
  const int lane = tid & 63;
  const int wv = tid >> 6;
  const int wm = wv >> 1, wn = wv & 1;
  const int l16 = lane & 15, quad = lane >> 4;
  const long tile_m = (long)bx * TM;
  const long tile_n = (long)by * 128;

  f32x4 z4 = {0.f, 0.f, 0.f, 0.f};
  f32x4 acc[IT][4];
#pragma unroll
  for (int i = 0; i < IT; i++)
#pragma unroll
    for (int j = 0; j < 4; j++) acc[i][j] = z4;

  for (int k0 = 0; k0 < K; k0 += 32) {
#pragma unroll
    for (int it = 0; it < TM / 64; it++) {
      int lin = it * 256 + tid;
      int row = lin >> 2, cc = lin & 3;
      glds16(A + (tile_m + row) * K + k0 + ((cc ^ ((row >> 1) & 3)) << 3), As + lin * 8);
    }
#pragma unroll
    for (int it = 0; it < 2; it++) {
      int lin = it * 256 + tid;
      int row = lin >> 2, cc = lin & 3;
      glds16(W + (tile_n + row) * K + k0 + ((cc ^ ((row >> 1) & 3)) << 3), Bs + lin * 8);
    }
    __syncthreads();
    bf16x8 af[IT], bfr[4];
#pragma unroll
    for (int i = 0; i < IT; i++) {
      int row = wm * (IT * 16) + i * 16 + l16;
      af[i] = *(const bf16x8*)(As + row * 32 + ((quad ^ ((row >> 1) & 3)) << 3));
    }
#pragma unroll
    for (int j = 0; j < 4; j++) {
      int row = wn * 64 + j * 16 + l16;
      bfr[j] = *(const bf16x8*)(Bs + row * 32 + ((quad ^ ((row >> 1) & 3)) << 3));
    }
#pragma unroll
    for (int i = 0; i < IT; i++)
#pragma unroll
      for (int j = 0; j < 4; j++) acc[i][j] = mfma16(af[i], bfr[j], acc[i][j]);
    __syncthreads();
  }

  // epilogue: C/D layout col=lane&15, row=quad*4+r
#pragma unroll
  for (int j = 0; j < 4; j++) {
    int gn = (int)tile_n + wn * 64 + j * 16 + l16;
    float bv = bias[gn];
#pragma unroll
    for (int i = 0; i < IT; i++) {
#pragma unroll
      for (int r = 0; r < 4; r++) {
        long gm = tile_m + wm * (IT * 16) + i * 16 + quad * 4 + r;
        float v = acc[i][j][r] + bv;
        if (mode == 3) {
          long idx = gm * EMBED + gn;
          ((float*)outp)[idx] = v + resid[idx];
        } else {
          if (mode == 0) v *= QSCALE;
          int b = (int)(gm >> 11), l = (int)(gm & 2047);
          int h = gn >> 6, dh = gn & 63;
          long idx;
          if (mode == 2)
            idx = (long)((b * HEADS + h) * DH + dh) * LQ + l;       // V transposed
          else
            idx = (long)((b * HEADS + h) * LQ + l) * DH + dh;       // Q, K
          ((u16*)outp)[idx] = f2bf(v);
        }
      }
    }
  }
}

__global__ __launch_bounds__(256) void qkv_kernel(
    const u16* __restrict__ qb, const u16* __restrict__ kvb,
    const u16* __restrict__ wqb, const u16* __restrict__ wkb, const u16* __restrict__ wvb,
    const float* __restrict__ bq, const float* __restrict__ bk, const float* __restrict__ bv,
    u16* __restrict__ Qh, u16* __restrict__ Kh, u16* __restrict__ Vt) {
  __shared__ u16 As[128 * 32];
  __shared__ u16 Bs[128 * 32];
  if (blockIdx.z == 0)      gemm_core<4>(As, Bs, qb,  wqb, bq, nullptr, Qh, 0, blockIdx.x, blockIdx.y);
  else if (blockIdx.z == 1) gemm_core<4>(As, Bs, kvb, wkb, bk, nullptr, Kh, 1, blockIdx.x, blockIdx.y);
  else                      gemm_core<4>(As, Bs, kvb, wvb, bv, nullptr, Vt, 2, blockIdx.x, blockIdx.y);
}

__global__ __launch_bounds__(256) void oproj_kernel(
    const u16* __restrict__ ctx, const u16* __restrict__ wob,
    const float* __restrict__ bo, const float* __restrict__ resid, float* __restrict__ out) {
  __shared__ u16 As[64 * 32];
  __shared__ u16 Bs[128 * 32];
  gemm_core<2>(As, Bs, ctx, wob, bo, resid, out, 3, blockIdx.x, blockIdx.y);
}

// ------------- flash attention, 32x32 MFMA, transposed formulation -----------
// Block = 4 waves x 32 qrows = 128 qrows; 64-key iterations.
// S^T = K.Q^T (Q B-frags hoisted, read once); P in padded LDS rows (144 B
// stride -> balanced min-phase banks for b64 writes and b128 reads);
// O^T = V^T.P (V staged in LDS); per-lane scalar lsum, 1 shuffle at end.
// 32x32x16 layouts: A/B m|n=lane&31, k=8*(lane>>5)+j;
// C/D col=lane&31, row=(reg&3)+8*(reg>>2)+4*(lane>>5).
#define PSTR 72  // P row stride in elements (64 keys + 8 pad = 144 B)
__global__ __launch_bounds__(256, 2) void attn_kernel(
    const u16* __restrict__ Qh, const u16* __restrict__ Kh,
    const u16* __restrict__ Vt, u16* __restrict__ ctx) {
  __shared__ u16 Qs[128 * 64];     // 16 KB
  __shared__ u16 Ks[64 * 64];      // 8 KB  [key][d]
  __shared__ u16 Vts[64 * 64];     // 8 KB  [d][key]
  __shared__ u16 Pts[128 * PSTR];  // 18 KB [qrow][key]
  const int tid = threadIdx.x;
  const int lane = tid & 63;
  const int wv = tid >> 6;             // wave owns qrows wv*32 .. wv*32+31
  const int l32 = lane & 31, h = lane >> 5;
  const int qt = blockIdx.x, bh = blockIdx.y;
  const long qoff = (long)bh * (LQ * DH) + (long)qt * (128 * DH);
  const long koff = (long)bh * (LQ * DH);
  const long voff = (long)bh * (DH * LQ);
  const int qbase = wv * 32;

  // stage Q tile 128x64 (global-side swizzled chunks)
#pragma unroll
  for (int it = 0; it < 4; it++) {
    int lin = it * 256 + tid;
    int row = lin >> 3, cc = lin & 7;
    glds16(Qh + qoff + row * 64 + ((cc ^ (row & 7)) << 3), Qs + lin * 8);
  }
  __syncthreads();

  // hoisted Q B-frags: n = qbase+l32, kstep ks: d = ks*16 + 8h + (0..7)
  bf16x8 bq[4];
  {
    int row = qbase + l32;
#pragma unroll
    for (int ks = 0; ks < 4; ks++)
      bq[ks] = *(const bf16x8*)(Qs + row * 64 + (((ks * 2 + h) ^ (row & 7)) << 3));
  }

  f32x16 z16 = {0.f, 0.f, 0.f, 0.f, 0.f, 0.f, 0.f, 0.f,
                0.f, 0.f, 0.f, 0.f, 0.f, 0.f, 0.f, 0.f};
  f32x16 ot[2];
  ot[0] = z16;
  ot[1] = z16;
  float lsum = 0.f;
  const int prow = qbase + l32;

  for (int kt = 0; kt < 32; kt++) {
    // stage K [key][d] and V^T [d][key] tiles
#pragma unroll
    for (int it = 0; it < 2; it++) {
      int lin = it * 256 + tid;
      int row = lin >> 3, cc = lin & 7;
      glds16(Kh + koff + (long)(kt * 64 + row) * 64 + ((cc ^ (row & 7)) << 3), Ks + lin * 8);
    }
#pragma unroll
    for (int it = 0; it < 2; it++) {
      int lin = it * 256 + tid;
      int row = lin >> 3, cc = lin & 7;
      glds16(Vt + voff + (long)row * LQ + kt * 64 + ((cc ^ (row & 7)) << 3), Vts + lin * 8);
    }
    __syncthreads();

    // S^T = K . Q^T : 64 keys (2 m-tiles) x 32 qrows, d = 4 ksteps of 16
    f32x16 st[2];
    st[0] = z16;
    st[1] = z16;
#pragma unroll
    for (int ks = 0; ks < 4; ks++) {
#pragma unroll
      for (int mt = 0; mt < 2; mt++) {
        int row = mt * 32 + l32;
        bf16x8 ak = *(const bf16x8*)(Ks + row * 64 + (((ks * 2 + h) ^ (row & 7)) << 3));
        st[mt] = mfma32(ak, bq[ks], st[mt]);
      }
    }

    // p = 2^s; lane's scores: qrow = prow, keys mt*32 + g*8 + 4h + r
#pragma unroll
    for (int mt = 0; mt < 2; mt++) {
#pragma unroll
      for (int g = 0; g < 4; g++) {
        float p0 = exp2f(st[mt][g * 4 + 0]);
        float p1 = exp2f(st[mt][g * 4 + 1]);
        float p2 = exp2f(st[mt][g * 4 + 2]);
        float p3 = exp2f(st[mt][g * 4 + 3]);
        lsum += (p0 + p1) + (p2 + p3);
        u32 lo = __builtin_amdgcn_perm(__float_as_uint(p1), __float_as_uint(p0), 0x07060302u);
        u32 hi = __builtin_amdgcn_perm(__float_as_uint(p3), __float_as_uint(p2), 0x07060302u);
        uint2 pk;
        pk.x = lo; pk.y = hi;
        *(uint2*)(Pts + prow * PSTR + mt * 32 + g * 8 + 4 * h) = pk;
      }
    }

    // O^T += V^T . P : m = d (2 tiles), n = 32 qrows, k = 64 keys (4 ksteps)
    // (P rows are same-wave; LDS ops in-order within wave => no barrier)
#pragma unroll
    for (int ks = 0; ks < 4; ks++) {
      bf16x8 bp = *(const bf16x8*)(Pts + prow * PSTR + ks * 16 + 8 * h);
#pragma unroll
      for (int mt = 0; mt < 2; mt++) {
        int row = mt * 32 + l32;
        bf16x8 av = *(const bf16x8*)(Vts + row * 64 + (((ks * 2 + h) ^ (row & 7)) << 3));
        ot[mt] = mfma32(av, bp, ot[mt]);
      }
    }
    __syncthreads();
  }

  // combine the two lane-halves holding the same qrow
  lsum += __shfl_xor(lsum, 32);
  float inv = 1.0f / lsum;

  // epilogue: lane holds qrow = qt*128 + prow, d = mt*32 + g*8 + 4h + r
  const int b = bh >> 4, head = bh & 15;
  int qrow = qt * 128 + prow;
  long base = (long)(b * LQ + qrow) * EMBED + head * DH;
#pragma unroll
  for (int mt = 0; mt < 2; mt++) {
#pragma unroll
    for (int g = 0; g < 4; g++) {
      u32 lo = (u32)f2bf(ot[mt][g * 4 + 0] * inv) | ((u32)f2bf(ot[mt][g * 4 + 1] * inv) << 16);
      u32 hi = (u32)f2bf(ot[mt][g * 4 + 2] * inv) | ((u32)f2bf(ot[mt][g * 4 + 3] * inv) << 16);
      uint2 pk;
      pk.x = lo; pk.y = hi;
      *(uint2*)(ctx + base + mt * 32 + g * 8 + 4 * h) = pk;
    }
  }
}

// ---------------- LayerNorm in place on d_out ----------------
__global__ __launch_bounds__(256) void ln_kernel(
    float* __restrict__ x, const float* __restrict__ gamma, const float* __restrict__ beta) {
  __shared__ float red[8];
  const int tid = threadIdx.x;
  const long row = blockIdx.x;
  float4 v = *(const float4*)(x + row * EMBED + tid * 4);
  float s = v.x + v.y + v.z + v.w;
  float sq = v.x * v.x + v.y * v.y + v.z * v.z + v.w * v.w;
#pragma unroll
  for (int off = 1; off < 64; off <<= 1) {
    s += __shfl_xor(s, off);
    sq += __shfl_xor(sq, off);
  }
  if ((tid & 63) == 0) {
    red[(tid >> 6) * 2] = s;
    red[(tid >> 6) * 2 + 1] = sq;
  }
  __syncthreads();
  s = red[0] + red[2] + red[4] + red[6];
  sq = red[1] + red[3] + red[5] + red[7];
  float mu = s * (1.f / EMBED);
  float var = sq * (1.f / EMBED) - mu * mu;
  float rstd = rsqrtf(var + 1e-5f);
  float4 g = *(const float4*)(gamma + tid * 4);
  float4 bt = *(const float4*)(beta + tid * 4);
  float4 ov;
  ov.x = (v.x - mu) * rstd * g.x + bt.x;
  ov.y = (v.y - mu) * rstd * g.y + bt.y;
  ov.z = (v.z - mu) * rstd * g.z + bt.z;
  ov.w = (v.w - mu) * rstd * g.w + bt.w;
  *(float4*)(x + row * EMBED + tid * 4) = ov;
}

extern "C" void kernel_launch(void* const* d_in, const int* in_sizes, int n_in,
                              void* d_out, int out_size, void* d_ws, size_t ws_size,
                              hipStream_t stream) {
  const float* q     = (const float*)d_in[0];
  const float* kv    = (const float*)d_in[1];
  // d_in[2] = prompt_size (0, unused)
  const float* Wq    = (const float*)d_in[3];
  const float* bq    = (const float*)d_in[4];
  const float* Wk    = (const float*)d_in[5];
  const float* bk    = (const float*)d_in[6];
  const float* Wv    = (const float*)d_in[7];
  const float* bv    = (const float*)d_in[8];
  const float* Wo    = (const float*)d_in[9];
  const float* bo    = (const float*)d_in[10];
  const float* gamma = (const float*)d_in[11];
  const float* beta  = (const float*)d_in[12];

  char* ws = (char*)d_ws;
  u16* qb  = (u16*)(ws + (0l  << 20));  // 8 MB
  u16* kvb = (u16*)(ws + (8l  << 20));  // 8 MB
  u16* wqb = (u16*)(ws + (16l << 20));  // 2 MB
  u16* wkb = (u16*)(ws + (18l << 20));
  u16* wvb = (u16*)(ws + (20l << 20));
  u16* wob = (u16*)(ws + (22l << 20));
  u16* Qh  = (u16*)(ws + (24l << 20));  // 8 MB [bh][L][64] (pre-scaled by QSCALE)
  u16* Kh  = (u16*)(ws + (32l << 20));  // 8 MB [bh][L][64]
  u16* Vt  = (u16*)(ws + (40l << 20));  // 8 MB [bh][64][L]
  u16* ctx = (u16*)(ws + (48l << 20));  // 8 MB [B][L][E]   (total 56 MB)
  float* out = (float*)d_out;

  cast_kernel<<<6144, 256, 0, stream>>>(q, kv, Wq, Wk, Wv, Wo, qb, kvb, wqb, wkb, wvb, wob);
  qkv_kernel<<<dim3(32, 8, 3), 256, 0, stream>>>(qb, kvb, wqb, wkb, wvb, bq, bk, bv, Qh, Kh, Vt);
  attn_kernel<<<dim3(16, 32), 256, 0, stream>>>(Qh, Kh, Vt, ctx);
  oproj_kernel<<<dim3(64, 8), 256, 0, stream>>>(ctx, wob, bo, q, out);
  ln_kernel<<<4096, 256, 0, stream>>>(out, gamma, beta);
}